// Round 6
// baseline (345.861 us; speedup 1.0000x reference)
//
#include <hip/hip_runtime.h>
#include <hip/hip_bf16.h>

typedef short short8 __attribute__((ext_vector_type(8)));
typedef short short4v __attribute__((ext_vector_type(4)));
typedef float f32x4 __attribute__((ext_vector_type(4)));

#define NB 2
#define NS 1024
#define NC 640
#define NH 8
#define ND 80
#define NRF 4
#define NL 5120
#define EPSF 1e-5f
// 80^-0.5 * log2(e): fold attention scale + base-2 exp into q
#define QSCL 0.16129861f

__device__ __forceinline__ unsigned short f2bf(float f){
  unsigned int u = __float_as_uint(f);
  u += 0x7FFFu + ((u>>16)&1u);          // RNE
  return (unsigned short)(u>>16);
}
__device__ __forceinline__ float bf2f(unsigned short s){
  return __uint_as_float(((unsigned)s)<<16);
}

// ---------------- cast hidden_states -> bf16 ----------------
__global__ void __launch_bounds__(256) k_cast_hs(const float* __restrict__ hs,
                                                 unsigned short* __restrict__ X){
  int i = (blockIdx.x*256 + threadIdx.x)*4;
  const float4 v = *(const float4*)(hs + i);
  uint2 pk;
  pk.x = (unsigned)f2bf(v.x) | ((unsigned)f2bf(v.y)<<16);
  pk.y = (unsigned)f2bf(v.z) | ((unsigned)f2bf(v.w)<<16);
  *(uint2*)(X + i) = pk;
}

// ---------------- transpose weights -> WT[n][k] bf16 ----------------
__global__ void __launch_bounds__(256) k_transpose_w(const float* __restrict__ Wq,
    const float* __restrict__ Wk, const float* __restrict__ Wv, const float* __restrict__ Wo,
    unsigned short* __restrict__ WT){
  const float* W = (blockIdx.z==0)?Wq:(blockIdx.z==1)?Wk:(blockIdx.z==2)?Wv:Wo;
  unsigned short* out = WT + (size_t)blockIdx.z*NC*NC;
  int n0 = blockIdx.x*64, k0 = blockIdx.y*64;
  __shared__ unsigned short tile[64][65];
  int t = threadIdx.x;
  int cl = (t&15)*4, rl = t>>4;
  #pragma unroll
  for(int kk=0;kk<4;kk++){
    int kl = rl + kk*16;
    float4 v = *(const float4*)(W + (size_t)(k0+kl)*NC + n0 + cl);
    tile[kl][cl+0]=f2bf(v.x); tile[kl][cl+1]=f2bf(v.y);
    tile[kl][cl+2]=f2bf(v.z); tile[kl][cl+3]=f2bf(v.w);
  }
  __syncthreads();
  #pragma unroll
  for(int nn=0;nn<4;nn++){
    int nl = rl + nn*16;
    unsigned short a=tile[cl+0][nl], b=tile[cl+1][nl], c=tile[cl+2][nl], d=tile[cl+3][nl];
    uint2 pk; pk.x = (unsigned)a|((unsigned)b<<16); pk.y = (unsigned)c|((unsigned)d<<16);
    *(uint2*)(out + (size_t)(n0+nl)*NC + k0 + cl) = pk;
  }
}

// ---------------- QKV projection GEMM (bf16 MFMA) ----------------
__global__ void __launch_bounds__(256) k_gemm_qkv(const unsigned short* __restrict__ X,
    const unsigned short* __restrict__ WT, unsigned short* __restrict__ qbuf,
    unsigned short* __restrict__ kS, unsigned short* __restrict__ vTs){
  __shared__ unsigned short As[64*40], Bs[64*40];
  int mode = blockIdx.z;
  const unsigned short* Wt = WT + (size_t)mode*NC*NC;
  int M0 = blockIdx.x*64, N0 = blockIdx.y*64;
  int t = threadIdx.x, w = t>>6, lane = t&63, lr = lane&15, lg = lane>>4;
  int row = t>>2, seg = t&3;
  f32x4 acc[4];
  #pragma unroll
  for(int j=0;j<4;j++) acc[j] = (f32x4){0.f,0.f,0.f,0.f};
  for(int k0=0;k0<NC;k0+=32){
    uint4 a  = *(const uint4*)(X  + (size_t)(M0+row)*NC + k0 + seg*8);
    uint4 bq = *(const uint4*)(Wt + (size_t)(N0+row)*NC + k0 + seg*8);
    __syncthreads();
    *(uint4*)&As[row*40+seg*8] = a;
    *(uint4*)&Bs[row*40+seg*8] = bq;
    __syncthreads();
    short8 af = *(const short8*)&As[(w*16+lr)*40 + lg*8];
    #pragma unroll
    for(int j=0;j<4;j++){
      short8 bf = *(const short8*)&Bs[(j*16+lr)*40 + lg*8];
      acc[j] = __builtin_amdgcn_mfma_f32_16x16x32_bf16(af, bf, acc[j], 0,0,0);
    }
  }
  #pragma unroll
  for(int j=0;j<4;j++){
    int n = N0 + j*16 + lr;
    int h = n/ND, d = n - h*ND;
    #pragma unroll
    for(int r=0;r<4;r++){
      int m = M0 + w*16 + lg*4 + r;
      int b = m>>10, s = m&1023;
      float val = acc[j][r];
      if(mode==0){
        qbuf[(size_t)(((b<<3)|h)*NS + s)*ND + d] = f2bf(val*QSCL);
      } else if(mode==1){
        kS[(size_t)(((b<<3)|h)*NS + s)*ND + d] = f2bf(val);
      } else {
        vTs[(size_t)(((b<<3)|h)*ND + d)*NS + s] = f2bf(val);
      }
    }
  }
}

// ---------------- self-V stats from bf16 vTs rows (contiguous) ----------------
__global__ void __launch_bounds__(256) k_stats_self(const unsigned short* __restrict__ vTs,
    float* __restrict__ smean, float* __restrict__ sstd){
  int gw = blockIdx.x*4 + (threadIdx.x>>6);   // channel id over 2*640
  int lane = threadIdx.x&63;
  int b = gw/NC, c = gw%NC;
  int h = c/ND, d = c - h*ND;
  const unsigned short* row = vTs + (size_t)((b*NH + h)*ND + d)*NS;
  short8 v0 = *(const short8*)(row + lane*16);
  short8 v1 = *(const short8*)(row + lane*16 + 8);
  float sum=0.f, ss=0.f;
  #pragma unroll
  for(int j=0;j<8;j++){
    float x = bf2f((unsigned short)v0[j]); sum+=x; ss+=x*x;
    float y = bf2f((unsigned short)v1[j]); sum+=y; ss+=y*y;
  }
  #pragma unroll
  for(int m=1;m<=32;m<<=1){
    sum += __shfl_xor(sum, m);
    ss  += __shfl_xor(ss, m);
  }
  if(lane==0){
    float mean = sum*(1.f/1024.f);
    float var  = fmaxf(0.f,(ss - sum*sum*(1.f/1024.f))*(1.f/1023.f));
    smean[b*NC+c]=mean; sstd[b*NC+c]=sqrtf(var)+EPSF;
  }
}

// ---------------- ref-V stats (mean + unbiased std) from fp32 ----------------
__global__ void __launch_bounds__(256) k_stats_ref(const float* __restrict__ ref_value,
    float* __restrict__ cmean, float* __restrict__ cstd){
  int bid = blockIdx.x;                 // 80 = 10 cg x 4 src x 2 b
  int cg = bid%10, src = (bid/10)&3, b = bid/40;
  int t = threadIdx.x, cl = t&63, sg = t>>6;
  int c = cg*64 + cl;
  const float* base = ref_value + (size_t)(b*NRF + src)*NS*NC + c;
  float sum=0.f, ss=0.f;
  for(int i=0;i<256;i++){
    float x = base[(size_t)(sg*256+i)*NC];
    sum += x; ss += x*x;
  }
  __shared__ float r0[4][64], r1[4][64];
  r0[sg][cl]=sum; r1[sg][cl]=ss;
  __syncthreads();
  if(t<64){
    float S=0.f,Q=0.f;
    #pragma unroll
    for(int gg=0;gg<4;gg++){S+=r0[gg][t];Q+=r1[gg][t];}
    float mean = S*(1.f/1024.f);
    float var  = fmaxf(0.f,(Q - S*S*(1.f/1024.f))*(1.f/1023.f));
    int cc = cg*64+t;
    cmean[(b*NRF+src)*NC+cc]=mean;
    cstd[(b*NRF+src)*NC+cc]=sqrtf(var)+EPSF;
  }
}

__global__ void __launch_bounds__(256) k_scalebias(const float* __restrict__ smean,
    const float* __restrict__ sstd, const float* __restrict__ cmean, const float* __restrict__ cstd,
    float* __restrict__ scl, float* __restrict__ bia){
  int g = blockIdx.x*256+threadIdx.x;   // < 2*4*640
  int c = g%NC; int b = g/(NRF*NC);
  float sc = sstd[b*NC+c]/cstd[g];
  bia[g] = smean[b*NC+c] - cmean[g]*sc;
  scl[g] = sc;
}

// ---------------- flash attention (swapped-operand; refs read fp32 from d_in) ----------------
__global__ void __launch_bounds__(256) k_attn(const unsigned short* __restrict__ qbuf,
    const unsigned short* __restrict__ kS, const unsigned short* __restrict__ vTs,
    const float* __restrict__ ref_key, const float* __restrict__ ref_value,
    const float* __restrict__ scl, const float* __restrict__ bia,
    unsigned short* __restrict__ attnO){
  __shared__ unsigned short Ks[64*88];
  __shared__ unsigned short Vs[80*72];

  int p = blockIdx.x;
  // XCD swizzle: each XCD owns 32 consecutive logical blocks = 2 bh
  int logical = (p&7)*32 + (p>>3);
  int bh = logical>>4;
  int qti = logical&15;
  int b = bh>>3, h = bh&7;
  int t = threadIdx.x, w = t>>6, lane = t&63, lr = lane&15, lg = lane>>4;

  const unsigned short* kb = kS  + (size_t)bh*NS*ND;
  const unsigned short* vb = vTs + (size_t)bh*ND*NS;

  // Q fragments: this wave's 16 queries, B-operand (n=query=lane&15, k=d in-register)
  const unsigned short* qrow = qbuf + (size_t)(bh*NS + qti*64 + w*16 + lr)*ND;
  short8 qf0 = *(const short8*)(qrow + lg*8);
  short8 qf1 = *(const short8*)(qrow + 32 + lg*8);
  short4v q4 = *(const short4v*)(qrow + 64 + lg*4);
  short8 qft = {q4[0],q4[1],q4[2],q4[3],(short)0,(short)0,(short)0,(short)0};

  // self-K staging: 64 rows x 80 bf16 = 640 uint4 slots (10 segs/row) -- FIXED (was 5/row)
  int rowA = t/10,       segA = t - 10*(t/10);
  int rowB = (t+256)/10, segB = (t+256) - 10*((t+256)/10);
  int rowC = (t+512)/10, segC = (t+512) - 10*((t+512)/10);   // only t<128
  // self-V^T staging: 80 rows x 64 keys = 80 x 8 uint4
  int vd = t>>3, vs = t&7;

  f32x4 acc[5];
  #pragma unroll
  for(int dt=0;dt<5;dt++) acc[dt] = (f32x4){0.f,0.f,0.f,0.f};
  float mrun = -1e30f, lrun = 0.f;

  for(int i=0;i<80;i++){
    bool self = (i<16);
    uint4 ra, rb, rc, rv0, rv1, rv2;
    float4 kr4[5], vr4[5];
    int rr = 0, srow[5], sseg[5];
    if(self){
      int s0 = i*64;
      ra = *(const uint4*)(kb + (size_t)(s0+rowA)*ND + segA*8);
      rb = *(const uint4*)(kb + (size_t)(s0+rowB)*ND + segB*8);
      if(t<128) rc = *(const uint4*)(kb + (size_t)(s0+rowC)*ND + segC*8);
      rv0 = *(const uint4*)(vb + (size_t)vd*NS + s0 + vs*8);
      rv1 = *(const uint4*)(vb + (size_t)(vd+32)*NS + s0 + vs*8);
      if(t<128) rv2 = *(const uint4*)(vb + (size_t)(vd+64)*NS + s0 + vs*8);
    } else {
      int ri = i-16;
      rr = ri>>4;
      int s0 = (ri&15)*64;
      const float* kp = ref_key   + ((size_t)(b*NRF+rr)*NS + s0)*NC + h*ND;
      const float* vp = ref_value + ((size_t)(b*NRF+rr)*NS + s0)*NC + h*ND;
      #pragma unroll
      for(int kk=0;kk<5;kk++){
        int slot = t + kk*256;
        int row = slot/20, seg = slot - 20*(slot/20);
        srow[kk]=row; sseg[kk]=seg;
        kr4[kk] = *(const float4*)(kp + (size_t)row*NC + seg*4);
        vr4[kk] = *(const float4*)(vp + (size_t)row*NC + seg*4);
      }
    }
    __syncthreads();   // previous iteration's LDS reads complete
    if(self){
      *(uint4*)&Ks[rowA*88 + segA*8] = ra;
      *(uint4*)&Ks[rowB*88 + segB*8] = rb;
      if(t<128) *(uint4*)&Ks[rowC*88 + segC*8] = rc;
      *(uint4*)&Vs[vd*72 + vs*8] = rv0;
      *(uint4*)&Vs[(vd+32)*72 + vs*8] = rv1;
      if(t<128) *(uint4*)&Vs[(vd+64)*72 + vs*8] = rv2;
    } else {
      const float* sp = scl + (size_t)(b*NRF+rr)*NC + h*ND;
      const float* bp = bia + (size_t)(b*NRF+rr)*NC + h*ND;
      #pragma unroll
      for(int kk=0;kk<5;kk++){
        int row = srow[kk], seg = sseg[kk];
        // K: straight fp32->bf16
        uint2 pk;
        pk.x = (unsigned)f2bf(kr4[kk].x) | ((unsigned)f2bf(kr4[kk].y)<<16);
        pk.y = (unsigned)f2bf(kr4[kk].z) | ((unsigned)f2bf(kr4[kk].w)<<16);
        *(uint2*)&Ks[row*88 + seg*4] = pk;
        // V: AdaIN scale/bias then bf16, transposed into Vs[d][key]
        int c4 = seg*4;
        Vs[(c4+0)*72 + row] = f2bf(vr4[kk].x*sp[c4+0] + bp[c4+0]);
        Vs[(c4+1)*72 + row] = f2bf(vr4[kk].y*sp[c4+1] + bp[c4+1]);
        Vs[(c4+2)*72 + row] = f2bf(vr4[kk].z*sp[c4+2] + bp[c4+2]);
        Vs[(c4+3)*72 + row] = f2bf(vr4[kk].w*sp[c4+3] + bp[c4+3]);
      }
    }
    __syncthreads();

    // S^T tiles: A = K rows (m=key), B = Q (n=query); D=80 -> 2 full k32 + zero-padded tail
    f32x4 sc[4];
    #pragma unroll
    for(int mt=0;mt<4;mt++){
      const unsigned short* kr = &Ks[(mt*16+lr)*88];
      short8 kf0 = *(const short8*)(kr + lg*8);
      short8 kf1 = *(const short8*)(kr + 32 + lg*8);
      short4v k4 = *(const short4v*)(kr + 64 + lg*4);
      short8 kft = {k4[0],k4[1],k4[2],k4[3],(short)0,(short)0,(short)0,(short)0};
      f32x4 s = (f32x4){0.f,0.f,0.f,0.f};
      s = __builtin_amdgcn_mfma_f32_16x16x32_bf16(kf0, qf0, s, 0,0,0);
      s = __builtin_amdgcn_mfma_f32_16x16x32_bf16(kf1, qf1, s, 0,0,0);
      s = __builtin_amdgcn_mfma_f32_16x16x32_bf16(kft, qft, s, 0,0,0);
      sc[mt] = s;
    }

    // online softmax: lane owns query=lane&15, keys mt*16 + lg*4 + r
    float tmax = -1e30f;
    #pragma unroll
    for(int mt=0;mt<4;mt++){
      #pragma unroll
      for(int r=0;r<4;r++) tmax = fmaxf(tmax, sc[mt][r]);
    }
    tmax = fmaxf(tmax, __shfl_xor(tmax,16));
    tmax = fmaxf(tmax, __shfl_xor(tmax,32));
    float mnew = fmaxf(mrun, tmax);
    float corr = exp2f(mrun - mnew);
    float pvv[16]; float ps = 0.f;
    #pragma unroll
    for(int mt=0;mt<4;mt++){
      #pragma unroll
      for(int r=0;r<4;r++){ float e = exp2f(sc[mt][r]-mnew); pvv[mt*4+r]=e; ps+=e; }
    }
    ps += __shfl_xor(ps,16);
    ps += __shfl_xor(ps,32);
    lrun = lrun*corr + ps;
    mrun = mnew;
    #pragma unroll
    for(int dt=0;dt<5;dt++) acc[dt] *= corr;

    // P^T -> B operand; slot map kappa(lg,j): j<4 -> key u*32+4lg+j, j>=4 -> +16
    short8 pb[2];
    #pragma unroll
    for(int u=0;u<2;u++){
      #pragma unroll
      for(int j=0;j<4;j++){
        pb[u][j]   = (short)f2bf(pvv[u*8+j]);
        pb[u][4+j] = (short)f2bf(pvv[u*8+4+j]);
      }
    }
    // out^T += V^T * P^T ; A-frag keys read with the same kappa
    #pragma unroll
    for(int u=0;u<2;u++){
      #pragma unroll
      for(int dt=0;dt<5;dt++){
        const unsigned short* vr = &Vs[(dt*16+lr)*72 + u*32 + lg*4];
        short4v v0 = *(const short4v*)(vr);
        short4v v1 = *(const short4v*)(vr + 16);
        short8 vf = {v0[0],v0[1],v0[2],v0[3],v1[0],v1[1],v1[2],v1[3]};
        acc[dt] = __builtin_amdgcn_mfma_f32_16x16x32_bf16(vf, pb[u], acc[dt], 0,0,0);
      }
    }
  }

  // normalize + write attn (bf16, [B,S,C] with C = h*80+d)
  float inv = 1.f/lrun;
  unsigned short* orow = attnO + (size_t)(b*NS + qti*64 + w*16 + lr)*NC + h*ND;
  #pragma unroll
  for(int dt=0;dt<5;dt++){
    uint2 pk;
    pk.x = (unsigned)f2bf(acc[dt][0]*inv) | ((unsigned)f2bf(acc[dt][1]*inv)<<16);
    pk.y = (unsigned)f2bf(acc[dt][2]*inv) | ((unsigned)f2bf(acc[dt][3]*inv)<<16);
    *(uint2*)(orow + dt*16 + lg*4) = pk;
  }
}

// ---------------- output projection + bias -> fp32 out ----------------
__global__ void __launch_bounds__(256) k_gemm_out(const unsigned short* __restrict__ A,
    const unsigned short* __restrict__ WT, const float* __restrict__ bo, float* __restrict__ out){
  __shared__ unsigned short As[64*40], Bs[64*40];
  const unsigned short* Wt = WT + (size_t)3*NC*NC;
  int M0 = blockIdx.x*64, N0 = blockIdx.y*64;
  int t = threadIdx.x, w = t>>6, lane = t&63, lr = lane&15, lg = lane>>4;
  int row = t>>2, seg = t&3;
  f32x4 acc[4];
  #pragma unroll
  for(int j=0;j<4;j++) acc[j] = (f32x4){0.f,0.f,0.f,0.f};
  for(int k0=0;k0<NC;k0+=32){
    uint4 a  = *(const uint4*)(A  + (size_t)(M0+row)*NC + k0 + seg*8);
    uint4 bq = *(const uint4*)(Wt + (size_t)(N0+row)*NC + k0 + seg*8);
    __syncthreads();
    *(uint4*)&As[row*40+seg*8] = a;
    *(uint4*)&Bs[row*40+seg*8] = bq;
    __syncthreads();
    short8 af = *(const short8*)&As[(w*16+lr)*40 + lg*8];
    #pragma unroll
    for(int j=0;j<4;j++){
      short8 bf = *(const short8*)&Bs[(j*16+lr)*40 + lg*8];
      acc[j] = __builtin_amdgcn_mfma_f32_16x16x32_bf16(af, bf, acc[j], 0,0,0);
    }
  }
  #pragma unroll
  for(int j=0;j<4;j++){
    int n = N0 + j*16 + lr;
    float bb = bo[n];
    #pragma unroll
    for(int r=0;r<4;r++){
      int m = M0 + w*16 + lg*4 + r;
      out[(size_t)m*NC + n] = acc[j][r] + bb;
    }
  }
}

extern "C" void kernel_launch(void* const* d_in, const int* in_sizes, int n_in,
                              void* d_out, int out_size, void* d_ws, size_t ws_size,
                              hipStream_t stream) {
  const float* hs        = (const float*)d_in[0];
  const float* ref_key   = (const float*)d_in[1];
  const float* ref_value = (const float*)d_in[2];
  const float* Wq = (const float*)d_in[3];
  const float* Wk = (const float*)d_in[4];
  const float* Wv = (const float*)d_in[5];
  const float* Wo = (const float*)d_in[6];
  const float* bo = (const float*)d_in[7];
  float* out = (float*)d_out;

  char* ws = (char*)d_ws;
  size_t off = 0;
  auto alloc = [&](size_t bytes)->char*{
    char* p = ws + off;
    off += (bytes + 255) & ~(size_t)255;
    return p;
  };
  unsigned short* X    = (unsigned short*)alloc((size_t)NB*NS*NC*2);   // reused as attn
  unsigned short* WT   = (unsigned short*)alloc((size_t)4*NC*NC*2);
  unsigned short* qbuf = (unsigned short*)alloc((size_t)NB*NH*NS*ND*2);
  unsigned short* kS   = (unsigned short*)alloc((size_t)NB*NH*NS*ND*2);
  unsigned short* vTs  = (unsigned short*)alloc((size_t)NB*NH*ND*NS*2);
  float* smean = (float*)alloc((size_t)NB*NC*4);
  float* sstd  = (float*)alloc((size_t)NB*NC*4);
  float* cmean = (float*)alloc((size_t)NB*NRF*NC*4);
  float* cstd  = (float*)alloc((size_t)NB*NRF*NC*4);
  float* scl   = (float*)alloc((size_t)NB*NRF*NC*4);
  float* bia   = (float*)alloc((size_t)NB*NRF*NC*4);
  unsigned short* attn = X;   // lifetime-disjoint alias

  k_cast_hs<<<1280, 256, 0, stream>>>(hs, X);
  k_transpose_w<<<dim3(10,10,4), 256, 0, stream>>>(Wq, Wk, Wv, Wo, WT);
  k_gemm_qkv<<<dim3(32,10,3), 256, 0, stream>>>(X, WT, qbuf, kS, vTs);
  k_stats_self<<<320, 256, 0, stream>>>(vTs, smean, sstd);
  k_stats_ref<<<80, 256, 0, stream>>>(ref_value, cmean, cstd);
  k_scalebias<<<20, 256, 0, stream>>>(smean, sstd, cmean, cstd, scl, bia);
  k_attn<<<256, 256, 0, stream>>>(qbuf, kS, vTs, ref_key, ref_value, scl, bia, attn);
  k_gemm_out<<<dim3(32,10), 256, 0, stream>>>(attn, WT, bo, out);
}

// Round 8
// 237.358 us; speedup vs baseline: 1.4571x; 1.4571x over previous
//
#include <hip/hip_runtime.h>
#include <hip/hip_bf16.h>

typedef short short8 __attribute__((ext_vector_type(8)));
typedef short short4v __attribute__((ext_vector_type(4)));
typedef float f32x4 __attribute__((ext_vector_type(4)));

#define NB 2
#define NS 1024
#define NC 640
#define NH 8
#define ND 80
#define NRF 4
#define NL 5120
#define EPSF 1e-5f
// 80^-0.5 * log2(e): fold attention scale + base-2 exp into q
#define QSCL 0.16129861f

__device__ __forceinline__ unsigned short f2bf(float f){
  unsigned int u = __float_as_uint(f);
  u += 0x7FFFu + ((u>>16)&1u);          // RNE
  return (unsigned short)(u>>16);
}
__device__ __forceinline__ float bf2f(unsigned short s){
  return __uint_as_float(((unsigned)s)<<16);
}

// ---------------- cast hidden_states -> bf16 ----------------
__global__ void __launch_bounds__(256) k_cast_hs(const float* __restrict__ hs,
                                                 unsigned short* __restrict__ X){
  int i = (blockIdx.x*256 + threadIdx.x)*4;
  const float4 v = *(const float4*)(hs + i);
  uint2 pk;
  pk.x = (unsigned)f2bf(v.x) | ((unsigned)f2bf(v.y)<<16);
  pk.y = (unsigned)f2bf(v.z) | ((unsigned)f2bf(v.w)<<16);
  *(uint2*)(X + i) = pk;
}

// ---------------- transpose weights -> WT[n][k] bf16 ----------------
__global__ void __launch_bounds__(256) k_transpose_w(const float* __restrict__ Wq,
    const float* __restrict__ Wk, const float* __restrict__ Wv, const float* __restrict__ Wo,
    unsigned short* __restrict__ WT){
  const float* W = (blockIdx.z==0)?Wq:(blockIdx.z==1)?Wk:(blockIdx.z==2)?Wv:Wo;
  unsigned short* out = WT + (size_t)blockIdx.z*NC*NC;
  int n0 = blockIdx.x*64, k0 = blockIdx.y*64;
  __shared__ unsigned short tile[64][65];
  int t = threadIdx.x;
  int cl = (t&15)*4, rl = t>>4;
  #pragma unroll
  for(int kk=0;kk<4;kk++){
    int kl = rl + kk*16;
    float4 v = *(const float4*)(W + (size_t)(k0+kl)*NC + n0 + cl);
    tile[kl][cl+0]=f2bf(v.x); tile[kl][cl+1]=f2bf(v.y);
    tile[kl][cl+2]=f2bf(v.z); tile[kl][cl+3]=f2bf(v.w);
  }
  __syncthreads();
  #pragma unroll
  for(int nn=0;nn<4;nn++){
    int nl = rl + nn*16;
    unsigned short a=tile[cl+0][nl], b=tile[cl+1][nl], c=tile[cl+2][nl], d=tile[cl+3][nl];
    uint2 pk; pk.x = (unsigned)a|((unsigned)b<<16); pk.y = (unsigned)c|((unsigned)d<<16);
    *(uint2*)(out + (size_t)(n0+nl)*NC + k0 + cl) = pk;
  }
}

// ---------------- QKV projection GEMM (bf16 MFMA) ----------------
__global__ void __launch_bounds__(256) k_gemm_qkv(const unsigned short* __restrict__ X,
    const unsigned short* __restrict__ WT, unsigned short* __restrict__ qbuf,
    unsigned short* __restrict__ kext, unsigned short* __restrict__ vTx){
  __shared__ unsigned short As[64*40], Bs[64*40];
  int mode = blockIdx.z;
  const unsigned short* Wt = WT + (size_t)mode*NC*NC;
  int M0 = blockIdx.x*64, N0 = blockIdx.y*64;
  int t = threadIdx.x, w = t>>6, lane = t&63, lr = lane&15, lg = lane>>4;
  int row = t>>2, seg = t&3;
  f32x4 acc[4];
  #pragma unroll
  for(int j=0;j<4;j++) acc[j] = (f32x4){0.f,0.f,0.f,0.f};
  for(int k0=0;k0<NC;k0+=32){
    uint4 a  = *(const uint4*)(X  + (size_t)(M0+row)*NC + k0 + seg*8);
    uint4 bq = *(const uint4*)(Wt + (size_t)(N0+row)*NC + k0 + seg*8);
    __syncthreads();
    *(uint4*)&As[row*40+seg*8] = a;
    *(uint4*)&Bs[row*40+seg*8] = bq;
    __syncthreads();
    short8 af = *(const short8*)&As[(w*16+lr)*40 + lg*8];
    #pragma unroll
    for(int j=0;j<4;j++){
      short8 bf = *(const short8*)&Bs[(j*16+lr)*40 + lg*8];
      acc[j] = __builtin_amdgcn_mfma_f32_16x16x32_bf16(af, bf, acc[j], 0,0,0);
    }
  }
  #pragma unroll
  for(int j=0;j<4;j++){
    int n = N0 + j*16 + lr;
    int h = n/ND, d = n - h*ND;
    #pragma unroll
    for(int r=0;r<4;r++){
      int m = M0 + w*16 + lg*4 + r;
      int b = m>>10, s = m&1023;
      float val = acc[j][r];
      if(mode==0){
        qbuf[(size_t)(((b<<3)|h)*NS + s)*ND + d] = f2bf(val*QSCL);
      } else if(mode==1){
        kext[(size_t)(((b<<3)|h)*NL + s)*ND + d] = f2bf(val);
      } else {
        vTx[(size_t)(((b<<3)|h)*ND + d)*NL + s] = f2bf(val);
      }
    }
  }
}

// ---------------- self-V stats from bf16 vTx rows (contiguous) ----------------
__global__ void __launch_bounds__(256) k_stats_self(const unsigned short* __restrict__ vTx,
    float* __restrict__ smean, float* __restrict__ sstd){
  int gw = blockIdx.x*4 + (threadIdx.x>>6);   // channel id over 2*640
  int lane = threadIdx.x&63;
  int b = gw/NC, c = gw%NC;
  int h = c/ND, d = c - h*ND;
  const unsigned short* row = vTx + (size_t)((b*NH + h)*ND + d)*NL;
  short8 v0 = *(const short8*)(row + lane*16);
  short8 v1 = *(const short8*)(row + lane*16 + 8);
  float sum=0.f, ss=0.f;
  #pragma unroll
  for(int j=0;j<8;j++){
    float x = bf2f((unsigned short)v0[j]); sum+=x; ss+=x*x;
    float y = bf2f((unsigned short)v1[j]); sum+=y; ss+=y*y;
  }
  #pragma unroll
  for(int m=1;m<=32;m<<=1){
    sum += __shfl_xor(sum, m);
    ss  += __shfl_xor(ss, m);
  }
  if(lane==0){
    float mean = sum*(1.f/1024.f);
    float var  = fmaxf(0.f,(ss - sum*sum*(1.f/1024.f))*(1.f/1023.f));
    smean[b*NC+c]=mean; sstd[b*NC+c]=sqrtf(var)+EPSF;
  }
}

// ---------------- ref-V stats (mean + unbiased std) from fp32 ----------------
__global__ void __launch_bounds__(256) k_stats_ref(const float* __restrict__ ref_value,
    float* __restrict__ cmean, float* __restrict__ cstd){
  int bid = blockIdx.x;                 // 80 = 10 cg x 4 src x 2 b
  int cg = bid%10, src = (bid/10)&3, b = bid/40;
  int t = threadIdx.x, cl = t&63, sg = t>>6;
  int c = cg*64 + cl;
  const float* base = ref_value + (size_t)(b*NRF + src)*NS*NC + c;
  float sum=0.f, ss=0.f;
  for(int i=0;i<256;i++){
    float x = base[(size_t)(sg*256+i)*NC];
    sum += x; ss += x*x;
  }
  __shared__ float r0[4][64], r1[4][64];
  r0[sg][cl]=sum; r1[sg][cl]=ss;
  __syncthreads();
  if(t<64){
    float S=0.f,Q=0.f;
    #pragma unroll
    for(int gg=0;gg<4;gg++){S+=r0[gg][t];Q+=r1[gg][t];}
    float mean = S*(1.f/1024.f);
    float var  = fmaxf(0.f,(Q - S*S*(1.f/1024.f))*(1.f/1023.f));
    int cc = cg*64+t;
    cmean[(b*NRF+src)*NC+cc]=mean;
    cstd[(b*NRF+src)*NC+cc]=sqrtf(var)+EPSF;
  }
}

__global__ void __launch_bounds__(256) k_scalebias(const float* __restrict__ smean,
    const float* __restrict__ sstd, const float* __restrict__ cmean, const float* __restrict__ cstd,
    float* __restrict__ scl, float* __restrict__ bia){
  int g = blockIdx.x*256+threadIdx.x;   // < 2*4*640
  int c = g%NC; int b = g/(NRF*NC);
  float sc = sstd[b*NC+c]/cstd[g];
  bia[g] = smean[b*NC+c] - cmean[g]*sc;
  scl[g] = sc;
}

// ---------------- pack ref_key -> kext (head-split, bf16) ----------------
__global__ void __launch_bounds__(256) k_pack_k(const float* __restrict__ ref_key,
                                                unsigned short* __restrict__ kext){
  int g = blockIdx.x*256+threadIdx.x;
  size_t e = (size_t)g*4;
  int c = (int)(e%NC); int s = (int)((e/NC)&1023); int r = (int)((e/(NC*NS))&3); int b = (int)(e/((size_t)NC*NS*NRF));
  float4 v = *(const float4*)(ref_key + e);
  int h = c/ND, d = c - h*ND;
  uint2 pk;
  pk.x = (unsigned)f2bf(v.x)|((unsigned)f2bf(v.y)<<16);
  pk.y = (unsigned)f2bf(v.z)|((unsigned)f2bf(v.w)<<16);
  *(uint2*)(kext + (size_t)(((b<<3)|h)*NL + NS + r*NS + s)*ND + d) = pk;
}

// ---------------- pack ref_value -> vTx with AdaIN (LDS transpose) ----------------
__global__ void __launch_bounds__(256) k_pack_v(const float* __restrict__ ref_value,
    const float* __restrict__ scl, const float* __restrict__ bia, unsigned short* __restrict__ vTx){
  int bid=blockIdx.x;
  int ct=bid%10, st=(bid/10)&15, r=(bid/160)&3, b=bid/640;
  int c0=ct*64, s0=st*64;
  __shared__ float tile[64][68];
  int t=threadIdx.x;
  int cl=(t&15)*4, rl=t>>4;
  #pragma unroll
  for(int ss=0;ss<4;ss++){
    int srow = rl+ss*16;
    float4 v = *(const float4*)(ref_value + (size_t)((b*NRF+r)*NS + s0+srow)*NC + c0+cl);
    tile[srow][cl+0]=v.x; tile[srow][cl+1]=v.y; tile[srow][cl+2]=v.z; tile[srow][cl+3]=v.w;
  }
  __syncthreads();
  #pragma unroll
  for(int cc=0;cc<4;cc++){
    int crow = rl+cc*16;
    int c = c0+crow;
    float sc = scl[(b*NRF+r)*NC+c], bi = bia[(b*NRF+r)*NC+c];
    int h=c/ND, d=c-h*ND;
    unsigned short o0=f2bf(tile[(t&15)*4+0][crow]*sc+bi);
    unsigned short o1=f2bf(tile[(t&15)*4+1][crow]*sc+bi);
    unsigned short o2=f2bf(tile[(t&15)*4+2][crow]*sc+bi);
    unsigned short o3=f2bf(tile[(t&15)*4+3][crow]*sc+bi);
    uint2 pk; pk.x=(unsigned)o0|((unsigned)o1<<16); pk.y=(unsigned)o2|((unsigned)o3<<16);
    *(uint2*)(vTx + (size_t)(((b<<3)|h)*ND + d)*NL + NS + r*NS + s0 + (t&15)*4) = pk;
  }
}

// ---------------- flash attention (swapped-operand, 2-way KV split, uniform staging) ----------------
__global__ void __launch_bounds__(256) k_attn(const unsigned short* __restrict__ qbuf,
    const unsigned short* __restrict__ kext, const unsigned short* __restrict__ vTx,
    float* __restrict__ pacc0, float* __restrict__ pacc1, float* __restrict__ pml){
  __shared__ unsigned short Ks[64*88];
  __shared__ unsigned short Vs[80*88];

  int p = blockIdx.x;
  // XCD swizzle: each XCD owns 64 consecutive logical blocks = 2 bh; part pairs adjacent
  int logical = (p&7)*64 + (p>>3);
  int tile = logical>>1;                 // bh*16+qti
  int part = logical&1;
  int bh = tile>>4, qti = tile&15;
  int t = threadIdx.x, w = t>>6, lane = t&63, lr = lane&15, lg = lane>>4;

  const unsigned short* kb = kext + (size_t)bh*NL*ND;
  const unsigned short* vb = vTx  + (size_t)bh*ND*NL;

  // Q fragments: this wave's 16 queries, B-operand (n=query=lane&15, k=d in-register)
  const unsigned short* qrow = qbuf + (size_t)(bh*NS + qti*64 + w*16 + lr)*ND;
  short8 qf0 = *(const short8*)(qrow + lg*8);
  short8 qf1 = *(const short8*)(qrow + 32 + lg*8);
  short4v q4 = *(const short4v*)(qrow + 64 + lg*4);
  short8 qft = {q4[0],q4[1],q4[2],q4[3],(short)0,(short)0,(short)0,(short)0};

  // K staging: 64 rows x 80 bf16 = 640 uint4 slots (10 segs/row)
  int rowA = t/10,       segA = t - 10*(t/10);
  int rowB = (t+256)/10, segB = (t+256) - 10*((t+256)/10);
  int rowC = (t+512)/10, segC = (t+512) - 10*((t+512)/10);   // only t<128
  // V^T staging: 80 rows x 64 keys = 80 x 8 uint4
  int vd = t>>3, vs = t&7;

  f32x4 acc[5];
  #pragma unroll
  for(int dt=0;dt<5;dt++) acc[dt] = (f32x4){0.f,0.f,0.f,0.f};
  float mrun = -1e30f, lrun = 0.f;

  for(int i=0;i<40;i++){
    int key0 = (part*40 + i)*64;
    uint4 ra  = *(const uint4*)(kb + (size_t)(key0+rowA)*ND + segA*8);
    uint4 rb  = *(const uint4*)(kb + (size_t)(key0+rowB)*ND + segB*8);
    uint4 rc; if(t<128) rc = *(const uint4*)(kb + (size_t)(key0+rowC)*ND + segC*8);
    uint4 rv0 = *(const uint4*)(vb + (size_t)vd*NL + key0 + vs*8);
    uint4 rv1 = *(const uint4*)(vb + (size_t)(vd+32)*NL + key0 + vs*8);
    uint4 rv2; if(t<128) rv2 = *(const uint4*)(vb + (size_t)(vd+64)*NL + key0 + vs*8);
    __syncthreads();   // previous iteration's LDS reads complete
    *(uint4*)&Ks[rowA*88 + segA*8] = ra;
    *(uint4*)&Ks[rowB*88 + segB*8] = rb;
    if(t<128) *(uint4*)&Ks[rowC*88 + segC*8] = rc;
    *(uint4*)&Vs[vd*88 + vs*8] = rv0;
    *(uint4*)&Vs[(vd+32)*88 + vs*8] = rv1;
    if(t<128) *(uint4*)&Vs[(vd+64)*88 + vs*8] = rv2;
    __syncthreads();

    // S^T tiles: A = K rows (m=key), B = Q (n=query); D=80 -> 2 full k32 + zero-padded tail
    f32x4 sc[4];
    #pragma unroll
    for(int mt=0;mt<4;mt++){
      const unsigned short* kr = &Ks[(mt*16+lr)*88];
      short8 kf0 = *(const short8*)(kr + lg*8);
      short8 kf1 = *(const short8*)(kr + 32 + lg*8);
      short4v k4 = *(const short4v*)(kr + 64 + lg*4);
      short8 kft = {k4[0],k4[1],k4[2],k4[3],(short)0,(short)0,(short)0,(short)0};
      f32x4 s = (f32x4){0.f,0.f,0.f,0.f};
      s = __builtin_amdgcn_mfma_f32_16x16x32_bf16(kf0, qf0, s, 0,0,0);
      s = __builtin_amdgcn_mfma_f32_16x16x32_bf16(kf1, qf1, s, 0,0,0);
      s = __builtin_amdgcn_mfma_f32_16x16x32_bf16(kft, qft, s, 0,0,0);
      sc[mt] = s;
    }

    // online softmax: lane owns query=lane&15, keys mt*16 + lg*4 + r
    float tmax = -1e30f;
    #pragma unroll
    for(int mt=0;mt<4;mt++){
      #pragma unroll
      for(int r=0;r<4;r++) tmax = fmaxf(tmax, sc[mt][r]);
    }
    tmax = fmaxf(tmax, __shfl_xor(tmax,16));
    tmax = fmaxf(tmax, __shfl_xor(tmax,32));
    float mnew = fmaxf(mrun, tmax);
    float corr = exp2f(mrun - mnew);
    float pvv[16]; float ps = 0.f;
    #pragma unroll
    for(int mt=0;mt<4;mt++){
      #pragma unroll
      for(int r=0;r<4;r++){ float e = exp2f(sc[mt][r]-mnew); pvv[mt*4+r]=e; ps+=e; }
    }
    ps += __shfl_xor(ps,16);
    ps += __shfl_xor(ps,32);
    lrun = lrun*corr + ps;
    mrun = mnew;
    #pragma unroll
    for(int dt=0;dt<5;dt++) acc[dt] *= corr;

    // P^T -> B operand; slot map kappa(lg,j): j<4 -> key u*32+4lg+j, j>=4 -> +16
    short8 pb[2];
    #pragma unroll
    for(int u=0;u<2;u++){
      #pragma unroll
      for(int j=0;j<4;j++){
        pb[u][j]   = (short)f2bf(pvv[u*8+j]);
        pb[u][4+j] = (short)f2bf(pvv[u*8+4+j]);
      }
    }
    // out^T += V^T * P^T ; A-frag keys read with the same kappa
    #pragma unroll
    for(int u=0;u<2;u++){
      #pragma unroll
      for(int dt=0;dt<5;dt++){
        const unsigned short* vr = &Vs[(dt*16+lr)*88 + u*32 + lg*4];
        short4v v0 = *(const short4v*)(vr);
        short4v v1 = *(const short4v*)(vr + 16);
        short8 vf = {v0[0],v0[1],v0[2],v0[3],v1[0],v1[1],v1[2],v1[3]};
        acc[dt] = __builtin_amdgcn_mfma_f32_16x16x32_bf16(vf, pb[u], acc[dt], 0,0,0);
      }
    }
  }

  // write unnormalized partials + (m,l)
  float* pa = (part ? pacc1 : pacc0) + (size_t)tile*5120;
  int q = w*16 + lr;
  #pragma unroll
  for(int dt=0;dt<5;dt++){
    *(f32x4*)(pa + q*80 + dt*16 + lg*4) = acc[dt];
  }
  if(lg==0){
    pml[(size_t)logical*128 + q*2 + 0] = mrun;
    pml[(size_t)logical*128 + q*2 + 1] = lrun;
  }
}

// ---------------- combine the 2 KV partitions -> attn bf16 ----------------
__global__ void __launch_bounds__(256) k_combine(const float* __restrict__ pacc0,
    const float* __restrict__ pacc1, const float* __restrict__ pml,
    unsigned short* __restrict__ attnO){
  int tile = blockIdx.x;          // bh*16+qti
  int bh = tile>>4, qti = tile&15;
  int b = bh>>3, h = bh&7;
  int t = threadIdx.x;
  #pragma unroll
  for(int j=0;j<5;j++){
    int e = (t + j*256)*4;        // 5120 elems, 80%4==0 so q,d-block constant per quad
    int q = e/80, d = e - (e/80)*80;
    float m0 = pml[(size_t)(tile*2+0)*128 + q*2], l0 = pml[(size_t)(tile*2+0)*128 + q*2 + 1];
    float m1 = pml[(size_t)(tile*2+1)*128 + q*2], l1 = pml[(size_t)(tile*2+1)*128 + q*2 + 1];
    float mm = fmaxf(m0,m1);
    float c0 = exp2f(m0-mm), c1 = exp2f(m1-mm);
    float inv = 1.f/(l0*c0 + l1*c1);
    c0 *= inv; c1 *= inv;
    float4 a0 = *(const float4*)(pacc0 + (size_t)tile*5120 + e);
    float4 a1 = *(const float4*)(pacc1 + (size_t)tile*5120 + e);
    uint2 pk;
    pk.x = (unsigned)f2bf(a0.x*c0+a1.x*c1) | ((unsigned)f2bf(a0.y*c0+a1.y*c1)<<16);
    pk.y = (unsigned)f2bf(a0.z*c0+a1.z*c1) | ((unsigned)f2bf(a0.w*c0+a1.w*c1)<<16);
    *(uint2*)(attnO + (size_t)(b*NS + qti*64 + q)*NC + h*ND + d) = pk;
  }
}

// ---------------- output projection + bias -> fp32 out ----------------
__global__ void __launch_bounds__(256) k_gemm_out(const unsigned short* __restrict__ A,
    const unsigned short* __restrict__ WT, const float* __restrict__ bo, float* __restrict__ out){
  __shared__ unsigned short As[64*40], Bs[64*40];
  const unsigned short* Wt = WT + (size_t)3*NC*NC;
  int M0 = blockIdx.x*64, N0 = blockIdx.y*64;
  int t = threadIdx.x, w = t>>6, lane = t&63, lr = lane&15, lg = lane>>4;
  int row = t>>2, seg = t&3;
  f32x4 acc[4];
  #pragma unroll
  for(int j=0;j<4;j++) acc[j] = (f32x4){0.f,0.f,0.f,0.f};
  for(int k0=0;k0<NC;k0+=32){
    uint4 a  = *(const uint4*)(A  + (size_t)(M0+row)*NC + k0 + seg*8);
    uint4 bq = *(const uint4*)(Wt + (size_t)(N0+row)*NC + k0 + seg*8);
    __syncthreads();
    *(uint4*)&As[row*40+seg*8] = a;
    *(uint4*)&Bs[row*40+seg*8] = bq;
    __syncthreads();
    short8 af = *(const short8*)&As[(w*16+lr)*40 + lg*8];
    #pragma unroll
    for(int j=0;j<4;j++){
      short8 bf = *(const short8*)&Bs[(j*16+lr)*40 + lg*8];
      acc[j] = __builtin_amdgcn_mfma_f32_16x16x32_bf16(af, bf, acc[j], 0,0,0);
    }
  }
  #pragma unroll
  for(int j=0;j<4;j++){
    int n = N0 + j*16 + lr;
    float bb = bo[n];
    #pragma unroll
    for(int r=0;r<4;r++){
      int m = M0 + w*16 + lg*4 + r;
      out[(size_t)m*NC + n] = acc[j][r] + bb;
    }
  }
}

extern "C" void kernel_launch(void* const* d_in, const int* in_sizes, int n_in,
                              void* d_out, int out_size, void* d_ws, size_t ws_size,
                              hipStream_t stream) {
  const float* hs        = (const float*)d_in[0];
  const float* ref_key   = (const float*)d_in[1];
  const float* ref_value = (const float*)d_in[2];
  const float* Wq = (const float*)d_in[3];
  const float* Wk = (const float*)d_in[4];
  const float* Wv = (const float*)d_in[5];
  const float* Wo = (const float*)d_in[6];
  const float* bo = (const float*)d_in[7];
  float* out = (float*)d_out;

  char* ws = (char*)d_ws;
  size_t off = 0;
  auto alloc = [&](size_t bytes)->char*{
    char* p = ws + off;
    off += (bytes + 255) & ~(size_t)255;
    return p;
  };
  unsigned short* X    = (unsigned short*)alloc((size_t)NB*NS*NC*2);   // reused as attn
  unsigned short* WT   = (unsigned short*)alloc((size_t)4*NC*NC*2);
  unsigned short* qbuf = (unsigned short*)alloc((size_t)NB*NH*NS*ND*2);
  unsigned short* kext = (unsigned short*)alloc((size_t)NB*NH*NL*ND*2);
  unsigned short* vTx  = (unsigned short*)alloc((size_t)NB*NH*ND*NL*2);
  float* pacc1 = (float*)alloc((size_t)256*5120*4);
  float* pml   = (float*)alloc((size_t)512*128*4);
  float* smean = (float*)alloc((size_t)NB*NC*4);
  float* sstd  = (float*)alloc((size_t)NB*NC*4);
  float* cmean = (float*)alloc((size_t)NB*NRF*NC*4);
  float* cstd  = (float*)alloc((size_t)NB*NRF*NC*4);
  float* scl   = (float*)alloc((size_t)NB*NRF*NC*4);
  float* bia   = (float*)alloc((size_t)NB*NRF*NC*4);
  unsigned short* attn = X;     // lifetime-disjoint alias
  float* pacc0 = out;           // d_out as scratch: dead before k_gemm_out writes it

  k_cast_hs<<<1280, 256, 0, stream>>>(hs, X);
  k_transpose_w<<<dim3(10,10,4), 256, 0, stream>>>(Wq, Wk, Wv, Wo, WT);
  k_gemm_qkv<<<dim3(32,10,3), 256, 0, stream>>>(X, WT, qbuf, kext, vTx);
  k_pack_k<<<5120, 256, 0, stream>>>(ref_key, kext);
  k_stats_self<<<320, 256, 0, stream>>>(vTx, smean, sstd);
  k_stats_ref<<<80, 256, 0, stream>>>(ref_value, cmean, cstd);
  k_scalebias<<<20, 256, 0, stream>>>(smean, sstd, cmean, cstd, scl, bia);
  k_pack_v<<<1280, 256, 0, stream>>>(ref_value, scl, bia, vTx);
  k_attn<<<512, 256, 0, stream>>>(qbuf, kext, vTx, pacc0, pacc1, pml);
  k_combine<<<256, 256, 0, stream>>>(pacc0, pacc1, pml, attn);
  k_gemm_out<<<dim3(32,10), 256, 0, stream>>>(attn, WT, bo, out);
}

// Round 10
// 229.685 us; speedup vs baseline: 1.5058x; 1.0334x over previous
//
#include <hip/hip_runtime.h>
#include <hip/hip_bf16.h>

typedef short short8 __attribute__((ext_vector_type(8)));
typedef short short4v __attribute__((ext_vector_type(4)));
typedef float f32x4 __attribute__((ext_vector_type(4)));

#define NB 2
#define NS 1024
#define NC 640
#define NH 8
#define ND 80
#define NRF 4
#define NL 5120
#define EPSF 1e-5f
// 80^-0.5 * log2(e): fold attention scale + base-2 exp into q
#define QSCL 0.16129861f

__device__ __forceinline__ unsigned short f2bf(float f){
  unsigned int u = __float_as_uint(f);
  u += 0x7FFFu + ((u>>16)&1u);          // RNE
  return (unsigned short)(u>>16);
}
__device__ __forceinline__ float bf2f(unsigned short s){
  return __uint_as_float(((unsigned)s)<<16);
}

// ---------------- cast hidden_states -> bf16 ----------------
__global__ void __launch_bounds__(256) k_cast_hs(const float* __restrict__ hs,
                                                 unsigned short* __restrict__ X){
  int i = (blockIdx.x*256 + threadIdx.x)*4;
  const float4 v = *(const float4*)(hs + i);
  uint2 pk;
  pk.x = (unsigned)f2bf(v.x) | ((unsigned)f2bf(v.y)<<16);
  pk.y = (unsigned)f2bf(v.z) | ((unsigned)f2bf(v.w)<<16);
  *(uint2*)(X + i) = pk;
}

// ---------------- transpose weights -> WT[n][k] bf16 ----------------
__global__ void __launch_bounds__(256) k_transpose_w(const float* __restrict__ Wq,
    const float* __restrict__ Wk, const float* __restrict__ Wv, const float* __restrict__ Wo,
    unsigned short* __restrict__ WT){
  const float* W = (blockIdx.z==0)?Wq:(blockIdx.z==1)?Wk:(blockIdx.z==2)?Wv:Wo;
  unsigned short* out = WT + (size_t)blockIdx.z*NC*NC;
  int n0 = blockIdx.x*64, k0 = blockIdx.y*64;
  __shared__ unsigned short tile[64][65];
  int t = threadIdx.x;
  int cl = (t&15)*4, rl = t>>4;
  #pragma unroll
  for(int kk=0;kk<4;kk++){
    int kl = rl + kk*16;
    float4 v = *(const float4*)(W + (size_t)(k0+kl)*NC + n0 + cl);
    tile[kl][cl+0]=f2bf(v.x); tile[kl][cl+1]=f2bf(v.y);
    tile[kl][cl+2]=f2bf(v.z); tile[kl][cl+3]=f2bf(v.w);
  }
  __syncthreads();
  #pragma unroll
  for(int nn=0;nn<4;nn++){
    int nl = rl + nn*16;
    unsigned short a=tile[cl+0][nl], b=tile[cl+1][nl], c=tile[cl+2][nl], d=tile[cl+3][nl];
    uint2 pk; pk.x = (unsigned)a|((unsigned)b<<16); pk.y = (unsigned)c|((unsigned)d<<16);
    *(uint2*)(out + (size_t)(n0+nl)*NC + k0 + cl) = pk;
  }
}

// ---------------- QKV projection GEMM (bf16 MFMA) ----------------
__global__ void __launch_bounds__(256) k_gemm_qkv(const unsigned short* __restrict__ X,
    const unsigned short* __restrict__ WT, unsigned short* __restrict__ qbuf,
    unsigned short* __restrict__ kext, unsigned short* __restrict__ vTx){
  __shared__ unsigned short As[64*40], Bs[64*40];
  int mode = blockIdx.z;
  const unsigned short* Wt = WT + (size_t)mode*NC*NC;
  int M0 = blockIdx.x*64, N0 = blockIdx.y*64;
  int t = threadIdx.x, w = t>>6, lane = t&63, lr = lane&15, lg = lane>>4;
  int row = t>>2, seg = t&3;
  f32x4 acc[4];
  #pragma unroll
  for(int j=0;j<4;j++) acc[j] = (f32x4){0.f,0.f,0.f,0.f};
  for(int k0=0;k0<NC;k0+=32){
    uint4 a  = *(const uint4*)(X  + (size_t)(M0+row)*NC + k0 + seg*8);
    uint4 bq = *(const uint4*)(Wt + (size_t)(N0+row)*NC + k0 + seg*8);
    __syncthreads();
    *(uint4*)&As[row*40+seg*8] = a;
    *(uint4*)&Bs[row*40+seg*8] = bq;
    __syncthreads();
    short8 af = *(const short8*)&As[(w*16+lr)*40 + lg*8];
    #pragma unroll
    for(int j=0;j<4;j++){
      short8 bf = *(const short8*)&Bs[(j*16+lr)*40 + lg*8];
      acc[j] = __builtin_amdgcn_mfma_f32_16x16x32_bf16(af, bf, acc[j], 0,0,0);
    }
  }
  #pragma unroll
  for(int j=0;j<4;j++){
    int n = N0 + j*16 + lr;
    int h = n/ND, d = n - h*ND;
    #pragma unroll
    for(int r=0;r<4;r++){
      int m = M0 + w*16 + lg*4 + r;
      int b = m>>10, s = m&1023;
      float val = acc[j][r];
      if(mode==0){
        qbuf[(size_t)(((b<<3)|h)*NS + s)*ND + d] = f2bf(val*QSCL);
      } else if(mode==1){
        kext[(size_t)(((b<<3)|h)*NL + s)*ND + d] = f2bf(val);
      } else {
        vTx[(size_t)(((b<<3)|h)*ND + d)*NL + s] = f2bf(val);
      }
    }
  }
}

// ---------------- self-V stats from bf16 vTx rows (contiguous) ----------------
__global__ void __launch_bounds__(256) k_stats_self(const unsigned short* __restrict__ vTx,
    float* __restrict__ smean, float* __restrict__ sstd){
  int gw = blockIdx.x*4 + (threadIdx.x>>6);   // channel id over 2*640
  int lane = threadIdx.x&63;
  int b = gw/NC, c = gw%NC;
  int h = c/ND, d = c - h*ND;
  const unsigned short* row = vTx + (size_t)((b*NH + h)*ND + d)*NL;
  short8 v0 = *(const short8*)(row + lane*16);
  short8 v1 = *(const short8*)(row + lane*16 + 8);
  float sum=0.f, ss=0.f;
  #pragma unroll
  for(int j=0;j<8;j++){
    float x = bf2f((unsigned short)v0[j]); sum+=x; ss+=x*x;
    float y = bf2f((unsigned short)v1[j]); sum+=y; ss+=y*y;
  }
  #pragma unroll
  for(int m=1;m<=32;m<<=1){
    sum += __shfl_xor(sum, m);
    ss  += __shfl_xor(ss, m);
  }
  if(lane==0){
    float mean = sum*(1.f/1024.f);
    float var  = fmaxf(0.f,(ss - sum*sum*(1.f/1024.f))*(1.f/1023.f));
    smean[b*NC+c]=mean; sstd[b*NC+c]=sqrtf(var)+EPSF;
  }
}

// ---------------- ref-V stats (mean + unbiased std) from fp32 ----------------
__global__ void __launch_bounds__(256) k_stats_ref(const float* __restrict__ ref_value,
    float* __restrict__ cmean, float* __restrict__ cstd){
  int bid = blockIdx.x;                 // 80 = 10 cg x 4 src x 2 b
  int cg = bid%10, src = (bid/10)&3, b = bid/40;
  int t = threadIdx.x, cl = t&63, sg = t>>6;
  int c = cg*64 + cl;
  const float* base = ref_value + (size_t)(b*NRF + src)*NS*NC + c;
  float sum=0.f, ss=0.f;
  for(int i=0;i<256;i++){
    float x = base[(size_t)(sg*256+i)*NC];
    sum += x; ss += x*x;
  }
  __shared__ float r0[4][64], r1[4][64];
  r0[sg][cl]=sum; r1[sg][cl]=ss;
  __syncthreads();
  if(t<64){
    float S=0.f,Q=0.f;
    #pragma unroll
    for(int gg=0;gg<4;gg++){S+=r0[gg][t];Q+=r1[gg][t];}
    float mean = S*(1.f/1024.f);
    float var  = fmaxf(0.f,(Q - S*S*(1.f/1024.f))*(1.f/1023.f));
    int cc = cg*64+t;
    cmean[(b*NRF+src)*NC+cc]=mean;
    cstd[(b*NRF+src)*NC+cc]=sqrtf(var)+EPSF;
  }
}

// ---------------- pack ref_key -> kext (head-split, bf16) ----------------
__global__ void __launch_bounds__(256) k_pack_k(const float* __restrict__ ref_key,
                                                unsigned short* __restrict__ kext){
  int g = blockIdx.x*256+threadIdx.x;
  size_t e = (size_t)g*4;
  int c = (int)(e%NC); int s = (int)((e/NC)&1023); int r = (int)((e/(NC*NS))&3); int b = (int)(e/((size_t)NC*NS*NRF));
  float4 v = *(const float4*)(ref_key + e);
  int h = c/ND, d = c - h*ND;
  uint2 pk;
  pk.x = (unsigned)f2bf(v.x)|((unsigned)f2bf(v.y)<<16);
  pk.y = (unsigned)f2bf(v.z)|((unsigned)f2bf(v.w)<<16);
  *(uint2*)(kext + (size_t)(((b<<3)|h)*NL + NS + r*NS + s)*ND + d) = pk;
}

// ---------------- pack ref_value -> vTx with AdaIN (scale/bias inline) ----------------
__global__ void __launch_bounds__(256) k_pack_v(const float* __restrict__ ref_value,
    const float* __restrict__ smean, const float* __restrict__ sstd,
    const float* __restrict__ cmean, const float* __restrict__ cstd,
    unsigned short* __restrict__ vTx){
  int bid=blockIdx.x;
  int ct=bid%10, st=(bid/10)&15, r=(bid/160)&3, b=bid/640;
  int c0=ct*64, s0=st*64;
  __shared__ float tile[64][68];
  int t=threadIdx.x;
  int cl=(t&15)*4, rl=t>>4;
  #pragma unroll
  for(int ss=0;ss<4;ss++){
    int srow = rl+ss*16;
    float4 v = *(const float4*)(ref_value + (size_t)((b*NRF+r)*NS + s0+srow)*NC + c0+cl);
    tile[srow][cl+0]=v.x; tile[srow][cl+1]=v.y; tile[srow][cl+2]=v.z; tile[srow][cl+3]=v.w;
  }
  __syncthreads();
  #pragma unroll
  for(int cc=0;cc<4;cc++){
    int crow = rl+cc*16;
    int c = c0+crow;
    float sc = sstd[b*NC+c]/cstd[(b*NRF+r)*NC+c];
    float bi = smean[b*NC+c] - cmean[(b*NRF+r)*NC+c]*sc;
    int h=c/ND, d=c-h*ND;
    unsigned short o0=f2bf(tile[(t&15)*4+0][crow]*sc+bi);
    unsigned short o1=f2bf(tile[(t&15)*4+1][crow]*sc+bi);
    unsigned short o2=f2bf(tile[(t&15)*4+2][crow]*sc+bi);
    unsigned short o3=f2bf(tile[(t&15)*4+3][crow]*sc+bi);
    uint2 pk; pk.x=(unsigned)o0|((unsigned)o1<<16); pk.y=(unsigned)o2|((unsigned)o3<<16);
    *(uint2*)(vTx + (size_t)(((b<<3)|h)*ND + d)*NL + NS + r*NS + s0 + (t&15)*4) = pk;
  }
}

// ---------------- flash attention (swapped-operand, 4-way KV split) ----------------
__global__ void __launch_bounds__(256) k_attn(const unsigned short* __restrict__ qbuf,
    const unsigned short* __restrict__ kext, const unsigned short* __restrict__ vTx,
    float* __restrict__ pacc0, float* __restrict__ pacc1,
    float* __restrict__ pacc2, float* __restrict__ pacc3, float* __restrict__ pml){
  __shared__ unsigned short Ks[64*88];
  __shared__ unsigned short Vs[80*88];

  int p = blockIdx.x;
  // XCD swizzle: 1024 blocks, 8 XCDs, 128 consecutive logical per XCD = 2 bh
  int logical = (p&7)*128 + (p>>3);
  int tile = logical>>2;                 // bh*16+qti
  int part = logical&3;
  int bh = tile>>4, qti = tile&15;
  int t = threadIdx.x, w = t>>6, lane = t&63, lr = lane&15, lg = lane>>4;

  const unsigned short* kb = kext + (size_t)bh*NL*ND;
  const unsigned short* vb = vTx  + (size_t)bh*ND*NL;

  // Q fragments: this wave's 16 queries, B-operand (n=query=lane&15, k=d in-register)
  const unsigned short* qrow = qbuf + (size_t)(bh*NS + qti*64 + w*16 + lr)*ND;
  short8 qf0 = *(const short8*)(qrow + lg*8);
  short8 qf1 = *(const short8*)(qrow + 32 + lg*8);
  short4v q4 = *(const short4v*)(qrow + 64 + lg*4);
  short8 qft = {q4[0],q4[1],q4[2],q4[3],(short)0,(short)0,(short)0,(short)0};

  // K staging: 64 rows x 80 bf16 = 640 uint4 slots (10 segs/row)
  int rowA = t/10,       segA = t - 10*(t/10);
  int rowB = (t+256)/10, segB = (t+256) - 10*((t+256)/10);
  int rowC = (t+512)/10, segC = (t+512) - 10*((t+512)/10);   // only t<128
  // V^T staging: 80 rows x 64 keys = 80 x 8 uint4
  int vd = t>>3, vs = t&7;

  f32x4 acc[5];
  #pragma unroll
  for(int dt=0;dt<5;dt++) acc[dt] = (f32x4){0.f,0.f,0.f,0.f};
  float mrun = -1e30f, lrun = 0.f;

  for(int i=0;i<20;i++){
    int key0 = (part*20 + i)*64;
    uint4 ra  = *(const uint4*)(kb + (size_t)(key0+rowA)*ND + segA*8);
    uint4 rb  = *(const uint4*)(kb + (size_t)(key0+rowB)*ND + segB*8);
    uint4 rc; if(t<128) rc = *(const uint4*)(kb + (size_t)(key0+rowC)*ND + segC*8);
    uint4 rv0 = *(const uint4*)(vb + (size_t)vd*NL + key0 + vs*8);
    uint4 rv1 = *(const uint4*)(vb + (size_t)(vd+32)*NL + key0 + vs*8);
    uint4 rv2; if(t<128) rv2 = *(const uint4*)(vb + (size_t)(vd+64)*NL + key0 + vs*8);
    __syncthreads();   // previous iteration's LDS reads complete
    *(uint4*)&Ks[rowA*88 + segA*8] = ra;
    *(uint4*)&Ks[rowB*88 + segB*8] = rb;
    if(t<128) *(uint4*)&Ks[rowC*88 + segC*8] = rc;
    *(uint4*)&Vs[vd*88 + vs*8] = rv0;
    *(uint4*)&Vs[(vd+32)*88 + vs*8] = rv1;
    if(t<128) *(uint4*)&Vs[(vd+64)*88 + vs*8] = rv2;
    __syncthreads();

    // S^T tiles: A = K rows (m=key), B = Q (n=query); D=80 -> 2 full k32 + zero-padded tail
    f32x4 sc[4];
    #pragma unroll
    for(int mt=0;mt<4;mt++){
      const unsigned short* kr = &Ks[(mt*16+lr)*88];
      short8 kf0 = *(const short8*)(kr + lg*8);
      short8 kf1 = *(const short8*)(kr + 32 + lg*8);
      short4v k4 = *(const short4v*)(kr + 64 + lg*4);
      short8 kft = {k4[0],k4[1],k4[2],k4[3],(short)0,(short)0,(short)0,(short)0};
      f32x4 s = (f32x4){0.f,0.f,0.f,0.f};
      s = __builtin_amdgcn_mfma_f32_16x16x32_bf16(kf0, qf0, s, 0,0,0);
      s = __builtin_amdgcn_mfma_f32_16x16x32_bf16(kf1, qf1, s, 0,0,0);
      s = __builtin_amdgcn_mfma_f32_16x16x32_bf16(kft, qft, s, 0,0,0);
      sc[mt] = s;
    }

    // online softmax: lane owns query=lane&15, keys mt*16 + lg*4 + r
    float tmax = -1e30f;
    #pragma unroll
    for(int mt=0;mt<4;mt++){
      #pragma unroll
      for(int r=0;r<4;r++) tmax = fmaxf(tmax, sc[mt][r]);
    }
    tmax = fmaxf(tmax, __shfl_xor(tmax,16));
    tmax = fmaxf(tmax, __shfl_xor(tmax,32));

    float pvv[16];
    // T13 defer-max: skip rescale when no query's max grew by >8 (log2 units)
    if(__all(tmax <= mrun + 8.0f)){
      float ps = 0.f;
      #pragma unroll
      for(int mt=0;mt<4;mt++){
        #pragma unroll
        for(int r=0;r<4;r++){ float e = exp2f(sc[mt][r]-mrun); pvv[mt*4+r]=e; ps+=e; }
      }
      ps += __shfl_xor(ps,16);
      ps += __shfl_xor(ps,32);
      lrun += ps;
    } else {
      float mnew = fmaxf(mrun, tmax);
      float corr = exp2f(mrun - mnew);
      float ps = 0.f;
      #pragma unroll
      for(int mt=0;mt<4;mt++){
        #pragma unroll
        for(int r=0;r<4;r++){ float e = exp2f(sc[mt][r]-mnew); pvv[mt*4+r]=e; ps+=e; }
      }
      ps += __shfl_xor(ps,16);
      ps += __shfl_xor(ps,32);
      lrun = lrun*corr + ps;
      mrun = mnew;
      #pragma unroll
      for(int dt=0;dt<5;dt++) acc[dt] *= corr;
    }

    // P^T -> B operand; slot map kappa(lg,j): j<4 -> key u*32+4lg+j, j>=4 -> +16
    short8 pb[2];
    #pragma unroll
    for(int u=0;u<2;u++){
      #pragma unroll
      for(int j=0;j<4;j++){
        pb[u][j]   = (short)f2bf(pvv[u*8+j]);
        pb[u][4+j] = (short)f2bf(pvv[u*8+4+j]);
      }
    }
    // out^T += V^T * P^T ; A-frag keys read with the same kappa
    #pragma unroll
    for(int u=0;u<2;u++){
      #pragma unroll
      for(int dt=0;dt<5;dt++){
        const unsigned short* vr = &Vs[(dt*16+lr)*88 + u*32 + lg*4];
        short4v v0 = *(const short4v*)(vr);
        short4v v1 = *(const short4v*)(vr + 16);
        short8 vf = {v0[0],v0[1],v0[2],v0[3],v1[0],v1[1],v1[2],v1[3]};
        acc[dt] = __builtin_amdgcn_mfma_f32_16x16x32_bf16(vf, pb[u], acc[dt], 0,0,0);
      }
    }
  }

  // write unnormalized partials + (m,l)
  float* pa = (part==0?pacc0:part==1?pacc1:part==2?pacc2:pacc3) + (size_t)tile*5120;
  int q = w*16 + lr;
  #pragma unroll
  for(int dt=0;dt<5;dt++){
    *(f32x4*)(pa + q*80 + dt*16 + lg*4) = acc[dt];
  }
  if(lg==0){
    pml[(size_t)logical*128 + q*2 + 0] = mrun;
    pml[(size_t)logical*128 + q*2 + 1] = lrun;
  }
}

// ---------------- combine the 4 KV partitions -> attn bf16 ----------------
__global__ void __launch_bounds__(256) k_combine(const float* __restrict__ pacc0,
    const float* __restrict__ pacc1, const float* __restrict__ pacc2,
    const float* __restrict__ pacc3, const float* __restrict__ pml,
    unsigned short* __restrict__ attnO){
  int tile = blockIdx.x;          // bh*16+qti
  int bh = tile>>4, qti = tile&15;
  int b = bh>>3, h = bh&7;
  int t = threadIdx.x;
  #pragma unroll
  for(int j=0;j<5;j++){
    int e = (t + j*256)*4;        // 5120 elems; 80%4==0 so q constant per quad
    int q = e/80, d = e - (e/80)*80;
    float m0 = pml[(size_t)(tile*4+0)*128 + q*2], l0 = pml[(size_t)(tile*4+0)*128 + q*2 + 1];
    float m1 = pml[(size_t)(tile*4+1)*128 + q*2], l1 = pml[(size_t)(tile*4+1)*128 + q*2 + 1];
    float m2 = pml[(size_t)(tile*4+2)*128 + q*2], l2 = pml[(size_t)(tile*4+2)*128 + q*2 + 1];
    float m3 = pml[(size_t)(tile*4+3)*128 + q*2], l3 = pml[(size_t)(tile*4+3)*128 + q*2 + 1];
    float mm = fmaxf(fmaxf(m0,m1), fmaxf(m2,m3));
    float c0 = exp2f(m0-mm), c1 = exp2f(m1-mm), c2 = exp2f(m2-mm), c3 = exp2f(m3-mm);
    float inv = 1.f/(l0*c0 + l1*c1 + l2*c2 + l3*c3);
    c0 *= inv; c1 *= inv; c2 *= inv; c3 *= inv;
    float4 a0 = *(const float4*)(pacc0 + (size_t)tile*5120 + e);
    float4 a1 = *(const float4*)(pacc1 + (size_t)tile*5120 + e);
    float4 a2 = *(const float4*)(pacc2 + (size_t)tile*5120 + e);
    float4 a3 = *(const float4*)(pacc3 + (size_t)tile*5120 + e);
    uint2 pk;
    pk.x = (unsigned)f2bf(a0.x*c0+a1.x*c1+a2.x*c2+a3.x*c3)
         | ((unsigned)f2bf(a0.y*c0+a1.y*c1+a2.y*c2+a3.y*c3)<<16);
    pk.y = (unsigned)f2bf(a0.z*c0+a1.z*c1+a2.z*c2+a3.z*c3)
         | ((unsigned)f2bf(a0.w*c0+a1.w*c1+a2.w*c2+a3.w*c3)<<16);
    *(uint2*)(attnO + (size_t)(b*NS + qti*64 + q)*NC + h*ND + d) = pk;
  }
}

// ---------------- output projection + bias -> fp32 out ----------------
__global__ void __launch_bounds__(256) k_gemm_out(const unsigned short* __restrict__ A,
    const unsigned short* __restrict__ WT, const float* __restrict__ bo, float* __restrict__ out){
  __shared__ unsigned short As[64*40], Bs[64*40];
  const unsigned short* Wt = WT + (size_t)3*NC*NC;
  int M0 = blockIdx.x*64, N0 = blockIdx.y*64;
  int t = threadIdx.x, w = t>>6, lane = t&63, lr = lane&15, lg = lane>>4;
  int row = t>>2, seg = t&3;
  f32x4 acc[4];
  #pragma unroll
  for(int j=0;j<4;j++) acc[j] = (f32x4){0.f,0.f,0.f,0.f};
  for(int k0=0;k0<NC;k0+=32){
    uint4 a  = *(const uint4*)(A  + (size_t)(M0+row)*NC + k0 + seg*8);
    uint4 bq = *(const uint4*)(Wt + (size_t)(N0+row)*NC + k0 + seg*8);
    __syncthreads();
    *(uint4*)&As[row*40+seg*8] = a;
    *(uint4*)&Bs[row*40+seg*8] = bq;
    __syncthreads();
    short8 af = *(const short8*)&As[(w*16+lr)*40 + lg*8];
    #pragma unroll
    for(int j=0;j<4;j++){
      short8 bf = *(const short8*)&Bs[(j*16+lr)*40 + lg*8];
      acc[j] = __builtin_amdgcn_mfma_f32_16x16x32_bf16(af, bf, acc[j], 0,0,0);
    }
  }
  #pragma unroll
  for(int j=0;j<4;j++){
    int n = N0 + j*16 + lr;
    float bb = bo[n];
    #pragma unroll
    for(int r=0;r<4;r++){
      int m = M0 + w*16 + lg*4 + r;
      out[(size_t)m*NC + n] = acc[j][r] + bb;
    }
  }
}

extern "C" void kernel_launch(void* const* d_in, const int* in_sizes, int n_in,
                              void* d_out, int out_size, void* d_ws, size_t ws_size,
                              hipStream_t stream) {
  const float* hs        = (const float*)d_in[0];
  const float* ref_key   = (const float*)d_in[1];
  const float* ref_value = (const float*)d_in[2];
  const float* Wq = (const float*)d_in[3];
  const float* Wk = (const float*)d_in[4];
  const float* Wv = (const float*)d_in[5];
  const float* Wo = (const float*)d_in[6];
  const float* bo = (const float*)d_in[7];
  float* out = (float*)d_out;

  char* ws = (char*)d_ws;
  size_t off = 0;
  auto alloc = [&](size_t bytes)->char*{
    char* p = ws + off;
    off += (bytes + 255) & ~(size_t)255;
    return p;
  };
  unsigned short* X    = (unsigned short*)alloc((size_t)NB*NS*NC*2);   // reused as attn
  unsigned short* WT   = (unsigned short*)alloc((size_t)4*NC*NC*2);
  unsigned short* qbuf = (unsigned short*)alloc((size_t)NB*NH*NS*ND*2);
  unsigned short* kext = (unsigned short*)alloc((size_t)NB*NH*NL*ND*2);
  unsigned short* vTx  = (unsigned short*)alloc((size_t)NB*NH*ND*NL*2);
  float* pacc1 = (float*)alloc((size_t)256*5120*4);
  float* pacc2 = (float*)alloc((size_t)256*5120*4);
  float* pacc3 = (float*)alloc((size_t)256*5120*4);
  float* pml   = (float*)alloc((size_t)1024*128*4);
  float* smean = (float*)alloc((size_t)NB*NC*4);
  float* sstd  = (float*)alloc((size_t)NB*NC*4);
  float* cmean = (float*)alloc((size_t)NB*NRF*NC*4);
  float* cstd  = (float*)alloc((size_t)NB*NRF*NC*4);
  unsigned short* attn = X;     // lifetime-disjoint alias
  float* pacc0 = out;           // d_out as scratch: dead before k_gemm_out writes it

  k_cast_hs<<<1280, 256, 0, stream>>>(hs, X);
  k_transpose_w<<<dim3(10,10,4), 256, 0, stream>>>(Wq, Wk, Wv, Wo, WT);
  k_gemm_qkv<<<dim3(32,10,3), 256, 0, stream>>>(X, WT, qbuf, kext, vTx);
  k_pack_k<<<5120, 256, 0, stream>>>(ref_key, kext);
  k_stats_self<<<320, 256, 0, stream>>>(vTx, smean, sstd);
  k_stats_ref<<<80, 256, 0, stream>>>(ref_value, cmean, cstd);
  k_pack_v<<<1280, 256, 0, stream>>>(ref_value, smean, sstd, cmean, cstd, vTx);
  k_attn<<<1024, 256, 0, stream>>>(qbuf, kext, vTx, pacc0, pacc1, pacc2, pacc3, pml);
  k_combine<<<256, 256, 0, stream>>>(pacc0, pacc1, pacc2, pacc3, pml, attn);
  k_gemm_out<<<dim3(32,10), 256, 0, stream>>>(attn, WT, bo, out);
}